// Round 5
// baseline (294.382 us; speedup 1.0000x reference)
//
#include <hip/hip_runtime.h>
#include <math.h>

#define PHASE_BINS 100
#define EPSF 1e-10f
#define HW 262144           // 512*512
#define BATCH 64
#define BPB 32              // 2048 blocks = 8/CU, one full round
#define CHUNK (HW / BPB)    // 8192 elements per block
#define THREADS 256
#define GROUPS (CHUNK / (THREADS * 4))   // 8 groups of 4 elements per thread

typedef float f4 __attribute__((ext_vector_type(4)));

__device__ __forceinline__ float wave_reduce_sum(float v) {
    #pragma unroll
    for (int off = 32; off > 0; off >>= 1) v += __shfl_down(v, off, 64);
    return v;
}

// Volatile asm 16B load: cannot be sunk or coalesced away by the compiler.
__device__ __forceinline__ f4 ld16(const float* p) {
    f4 r;
    asm volatile("global_load_dwordx4 %0, %1, off" : "=v"(r) : "v"(p));
    return r;
}

// Counted vmem wait (T4): proceed while N loads remain in flight.
// rule #18: sched_barrier right after, so VALU can't hoist above the wait.
#define WAITCNT(N)                                            \
    do {                                                      \
        asm volatile("s_waitcnt vmcnt(" #N ")" ::: "memory"); \
        __builtin_amdgcn_sched_barrier(0);                    \
    } while (0)

// atan(z), z in [0,1]: A&S-style odd minimax poly, max err ~2e-8 rad.
__device__ __forceinline__ float atan01(float z) {
    float s = z * z;
    float p = fmaf(s, 0.0028662257f, -0.0161657367f);
    p = fmaf(s, p, 0.0429096138f);
    p = fmaf(s, p, -0.0752896400f);
    p = fmaf(s, p, 0.1065626393f);
    p = fmaf(s, p, -0.1420889944f);
    p = fmaf(s, p, 0.1999355085f);
    p = fmaf(s, p, -0.3333314528f);
    return fmaf(z * s, p, z);
}

// Branchless atan2 -> phase bin (verified absmax 0.0 rounds 1-4).
__device__ __forceinline__ int phase_bin(float y, float x) {
    const float PI_F = 3.14159265358979323846f;
    float ax = fabsf(x), ay = fabsf(y);
    float mx = fmaxf(ax, ay), mn = fminf(ax, ay);
    float r  = mn * __builtin_amdgcn_rcpf(mx);
    float th = atan01(r);
    th = (ay > ax) ? 1.57079632679f - th : th;
    th = (x < 0.0f) ? PI_F - th : th;
    th = (y < 0.0f) ? -th : th;
    int bin = (int)((th + PI_F) * 15.9154943092f);   // *100/(2pi)
    return min(max(bin, 0), PHASE_BINS - 1);
}

__global__ __launch_bounds__(THREADS, 8) void pass1_kernel(
    const float* __restrict__ A, const float* __restrict__ B,
    float* __restrict__ SA, float* __restrict__ SB, float* __restrict__ Tacc,
    unsigned int* __restrict__ histA, unsigned int* __restrict__ histB)
{
    __shared__ unsigned int h[2][4][PHASE_BINS];  // 800 words = 3.2 KB
    const int wave = threadIdx.x >> 6;
    const int lane = threadIdx.x & 63;

    for (int i = threadIdx.x; i < 2 * 4 * PHASE_BINS; i += THREADS)
        ((unsigned int*)h)[i] = 0u;
    __syncthreads();

    unsigned int* __restrict__ hA = &h[0][wave][0];
    unsigned int* __restrict__ hB = &h[1][wave][0];

    const int b   = blockIdx.x / BPB;
    const int blk = blockIdx.x % BPB;
    const size_t base = (size_t)b * (2 * HW);
    const int off0 = blk * CHUNK + threadIdx.x * 4;
    const float* pAr = A + base + off0;
    const float* pAi = pAr + HW;
    const float* pBr = B + base + off0;
    const float* pBi = pBr + HW;

    float sA = 0.f, sB = 0.f, t = 0.f;

    f4 c0[4], c1[4];   // ping-pong stage buffers

#define ISSUE(buf, g)                                   \
    do {                                                \
        buf[0] = ld16(pAr + (g) * (THREADS * 4));       \
        buf[1] = ld16(pAi + (g) * (THREADS * 4));       \
        buf[2] = ld16(pBr + (g) * (THREADS * 4));       \
        buf[3] = ld16(pBi + (g) * (THREADS * 4));       \
    } while (0)

#define PROC4(buf)                                                          \
    do {                                                                    \
        const float* arp = (const float*)&buf[0];                           \
        const float* aip = (const float*)&buf[1];                           \
        const float* brp = (const float*)&buf[2];                           \
        const float* bip = (const float*)&buf[3];                           \
        _Pragma("unroll")                                                   \
        for (int j = 0; j < 4; ++j) {                                       \
            float arj = arp[j], aij = aip[j];                               \
            float brj = brp[j], bij = bip[j];                               \
            float ra2 = fmaf(arj, arj, aij * aij);                          \
            float rb2 = fmaf(brj, brj, bij * bij);                          \
            float aa = __builtin_amdgcn_sqrtf(ra2);                         \
            float bb = __builtin_amdgcn_sqrtf(rb2);                         \
            sA += aa;                                                       \
            sB += bb;                                                       \
            float la = __log2f(fmaxf(ra2, 1e-37f));                         \
            float lb = __log2f(fmaxf(rb2, 1e-37f));                         \
            t = fmaf(aa * 0.34657359028f, la - lb, t);                      \
            atomicAdd(hA + phase_bin(aij, arj), 1u);                        \
            atomicAdd(hB + phase_bin(bij, brj), 1u);                        \
        }                                                                   \
    } while (0)

    // depth-2 pipeline, fully unrolled, static counted waits
    ISSUE(c0, 0);
    #pragma unroll
    for (int g = 0; g < GROUPS; g += 2) {
        ISSUE(c1, g + 1);               // outstanding: 8
        WAITCNT(4);                     // group g landed
        PROC4(c0);
        if (g + 2 < GROUPS) {
            ISSUE(c0, g + 2);           // outstanding: 8
            WAITCNT(4);                 // group g+1 landed
        } else {
            WAITCNT(0);                 // last group
        }
        PROC4(c1);
    }
#undef ISSUE
#undef PROC4

    sA = wave_reduce_sum(sA);
    sB = wave_reduce_sum(sB);
    t  = wave_reduce_sum(t);
    if (lane == 0) {
        atomicAdd(&SA[b], sA);
        atomicAdd(&SB[b], sB);
        atomicAdd(&Tacc[b], t);
    }

    __syncthreads();
    if (threadIdx.x < 2 * PHASE_BINS) {
        int hi  = threadIdx.x / PHASE_BINS;
        int bin = threadIdx.x % PHASE_BINS;
        unsigned v = h[hi][0][bin] + h[hi][1][bin] + h[hi][2][bin] + h[hi][3][bin];
        unsigned int* dst = hi ? histB : histA;
        atomicAdd(&dst[b * PHASE_BINS + bin], v);
    }
}

// pass2a: one wave per batch. Densities (fp32 torch edge widths), normalize,
// phase KL -> atomicAdd into phase_total; amplitude loss -> amp[b].
__global__ __launch_bounds__(64) void pass2a_kernel(
    const float* __restrict__ SA, const float* __restrict__ SB,
    const float* __restrict__ T,
    const unsigned int* __restrict__ histA, const unsigned int* __restrict__ histB,
    float* __restrict__ amp, float* __restrict__ phase_total)
{
    const int b = blockIdx.x;
    const int lane = threadIdx.x;
    const float PI_F = 3.14159265358979323846f;
    const float step = (2.0f * PI_F) / PHASE_BINS;

    float d_a[2], d_b[2];
    float sum_a = 0.f, sum_b = 0.f;
    #pragma unroll
    for (int r = 0; r < 2; ++r) {
        int bin = lane + r * 64;
        float da = 0.f, db = 0.f;
        if (bin < PHASE_BINS) {
            float e0 = -PI_F + bin * step;
            float e1 = (bin == PHASE_BINS - 1) ? PI_F : (-PI_F + (bin + 1) * step);
            float w = e1 - e0;                       // fp32 edge widths (torch density)
            float denom = (float)HW * w;
            da = (float)histA[b * PHASE_BINS + bin] / denom;
            db = (float)histB[b * PHASE_BINS + bin] / denom;
        }
        d_a[r] = da; d_b[r] = db;
        sum_a += da; sum_b += db;
    }
    #pragma unroll
    for (int off = 32; off > 0; off >>= 1) {
        sum_a += __shfl_xor(sum_a, off, 64);
        sum_b += __shfl_xor(sum_b, off, 64);
    }
    float kl = 0.f;
    #pragma unroll
    for (int r = 0; r < 2; ++r) {
        int bin = lane + r * 64;
        if (bin < PHASE_BINS) {
            float p = d_a[r] / (sum_a + EPSF);
            float q = d_b[r] / (sum_b + EPSF);
            kl += p * logf((p + EPSF) / (q + EPSF));
        }
    }
    #pragma unroll
    for (int off = 32; off > 0; off >>= 1) kl += __shfl_xor(kl, off, 64);

    if (lane == 0) {
        atomicAdd(phase_total, kl);
        float sa_raw = SA[b];
        float sa = sa_raw + EPSF;
        float sb = SB[b] + EPSF;
        amp[b] = T[b] / sa + (sa_raw / sa) * logf(sb / sa);
    }
}

__global__ __launch_bounds__(64) void pass2b_kernel(
    const float* __restrict__ amp, const float* __restrict__ phase_total,
    float* __restrict__ out)
{
    int b = threadIdx.x;
    out[b] = 0.5f * amp[b] + 0.5f * phase_total[0];
}

extern "C" void kernel_launch(void* const* d_in, const int* in_sizes, int n_in,
                              void* d_out, int out_size, void* d_ws, size_t ws_size,
                              hipStream_t stream) {
    const float* A = (const float*)d_in[0];
    const float* B = (const float*)d_in[1];
    float* out = (float*)d_out;

    float* SA = (float*)d_ws;
    float* SB = SA + BATCH;
    float* T  = SB + BATCH;
    unsigned int* histA = (unsigned int*)(T + BATCH);
    unsigned int* histB = histA + BATCH * PHASE_BINS;
    float* phase_total = (float*)(histB + BATCH * PHASE_BINS);
    float* amp = phase_total + 1;

    // zero SA/SB/T, both histograms, and phase_total
    size_t zero_bytes = (size_t)(3 * BATCH) * sizeof(float)
                      + (size_t)(2 * BATCH * PHASE_BINS) * sizeof(unsigned int)
                      + sizeof(float);
    hipMemsetAsync(d_ws, 0, zero_bytes, stream);

    pass1_kernel<<<dim3(BATCH * BPB), dim3(THREADS), 0, stream>>>(
        A, B, SA, SB, T, histA, histB);
    pass2a_kernel<<<dim3(BATCH), dim3(64), 0, stream>>>(
        SA, SB, T, histA, histB, amp, phase_total);
    pass2b_kernel<<<1, 64, 0, stream>>>(amp, phase_total, out);
}

// Round 6
// 285.791 us; speedup vs baseline: 1.0301x; 1.0301x over previous
//
#include <hip/hip_runtime.h>
#include <math.h>

#define PHASE_BINS 100
#define EPSF 1e-10f
#define HW 262144           // 512*512
#define BATCH 64
#define BPB 32              // 2048 blocks = 8/CU, one full round
#define CHUNK (HW / BPB)    // 8192 elements per block
#define THREADS 256
#define GROUPS (CHUNK / (THREADS * 4))   // 8 groups of 4 elements per thread

typedef float f4 __attribute__((ext_vector_type(4)));

__device__ __forceinline__ float wave_reduce_sum(float v) {
    #pragma unroll
    for (int off = 32; off > 0; off >>= 1) v += __shfl_down(v, off, 64);
    return v;
}

// Volatile asm 16B load: cannot be sunk or coalesced away by the compiler.
__device__ __forceinline__ f4 ld16(const float* p) {
    f4 r;
    asm volatile("global_load_dwordx4 %0, %1, off" : "=v"(r) : "v"(p));
    return r;
}

// Counted vmem wait (T4) + rule-18 fence.
#define WAITCNT(N)                                            \
    do {                                                      \
        asm volatile("s_waitcnt vmcnt(" #N ")" ::: "memory"); \
        __builtin_amdgcn_sched_barrier(0);                    \
    } while (0)

// phase bin, diet version (~25 VALU ops).
// atan poly: A&S 4.4.48 deg-7, |err| <= 1e-5 rad (bin width = 6.3e-2; the
// same quantizer is applied to BOTH P and Q histograms, so edge-shift error
// cancels to second order in the KL).
// Bin arithmetic: th2 = unsigned angle in [0,pi]; u = th2*S, b = floor(u);
//   y>=0: bin = 50 + b ;  y<0: bin = floor(50 - u) = 49 - b (a.s.)
// clamp handles the th2 = pi edge (u = 50.0000014 in fp32).
__device__ __forceinline__ int phase_bin(float y, float x) {
    float ax = fabsf(x), ay = fabsf(y);
    float mx = fmaxf(ax, ay), mn = fminf(ax, ay);
    float r  = mn * __builtin_amdgcn_rcpf(mx);
    float s  = r * r;
    float p  = fmaf(s, -0.0851330f, 0.1801410f);
    p = fmaf(s, p, -0.3302995f);
    p = fmaf(s, p, 0.9998660f);
    float th = r * p;                                  // atan(r), [0, pi/4]
    th = (ay > ax) ? 1.57079632679f - th : th;         // quadrant angle
    float th2 = (x < 0.0f) ? 3.14159265359f - th : th; // [0, pi]
    int b = (int)(th2 * 15.9154943092f);               // floor (th2 >= 0)
    int bin = (y < 0.0f) ? (49 - b) : (50 + b);
    return min(max(bin, 0), PHASE_BINS - 1);
}

__global__ __launch_bounds__(THREADS, 8) void pass1_kernel(
    const float* __restrict__ A, const float* __restrict__ B,
    float* __restrict__ SA, float* __restrict__ SB, float* __restrict__ Tacc,
    unsigned int* __restrict__ histA, unsigned int* __restrict__ histB)
{
    __shared__ unsigned int h[2][4][PHASE_BINS];  // 800 words = 3.2 KB
    const int wave = threadIdx.x >> 6;
    const int lane = threadIdx.x & 63;

    for (int i = threadIdx.x; i < 2 * 4 * PHASE_BINS; i += THREADS)
        ((unsigned int*)h)[i] = 0u;
    __syncthreads();

    unsigned int* __restrict__ hA = &h[0][wave][0];
    unsigned int* __restrict__ hB = &h[1][wave][0];

    const int b   = blockIdx.x / BPB;
    const int blk = blockIdx.x % BPB;
    const size_t base = (size_t)b * (2 * HW);
    const int off0 = blk * CHUNK + threadIdx.x * 4;
    const float* pAr = A + base + off0;
    const float* pAi = pAr + HW;
    const float* pBr = B + base + off0;
    const float* pBi = pBr + HW;

    float sA = 0.f, sB = 0.f, t = 0.f;

    f4 c0[4], c1[4];   // ping-pong stage buffers

#define ISSUE(buf, g)                                   \
    do {                                                \
        buf[0] = ld16(pAr + (g) * (THREADS * 4));       \
        buf[1] = ld16(pAi + (g) * (THREADS * 4));       \
        buf[2] = ld16(pBr + (g) * (THREADS * 4));       \
        buf[3] = ld16(pBi + (g) * (THREADS * 4));       \
    } while (0)

    // T accumulates sum aa*(log2(ra2) - log2(rb2)); the ln2/2 scale is
    // folded into pass2a (T_real = 0.34657359 * T).
#define PROC4(buf)                                                          \
    do {                                                                    \
        const float* arp = (const float*)&buf[0];                           \
        const float* aip = (const float*)&buf[1];                           \
        const float* brp = (const float*)&buf[2];                           \
        const float* bip = (const float*)&buf[3];                           \
        _Pragma("unroll")                                                   \
        for (int j = 0; j < 4; ++j) {                                       \
            float arj = arp[j], aij = aip[j];                               \
            float brj = brp[j], bij = bip[j];                               \
            float ra2 = fmaf(arj, arj, aij * aij);                          \
            float rb2 = fmaf(brj, brj, bij * bij);                          \
            float aa = __builtin_amdgcn_sqrtf(ra2);                         \
            float bb = __builtin_amdgcn_sqrtf(rb2);                         \
            sA += aa;                                                       \
            sB += bb;                                                       \
            float la = __log2f(fmaxf(ra2, 1e-37f));                         \
            float lb = __log2f(fmaxf(rb2, 1e-37f));                         \
            t = fmaf(aa, la - lb, t);                                       \
            atomicAdd(hA + phase_bin(aij, arj), 1u);                        \
            atomicAdd(hB + phase_bin(bij, brj), 1u);                        \
        }                                                                   \
    } while (0)

    // depth-2 pipeline, fully unrolled, static counted waits
    ISSUE(c0, 0);
    #pragma unroll
    for (int g = 0; g < GROUPS; g += 2) {
        ISSUE(c1, g + 1);               // outstanding: 8
        WAITCNT(4);                     // group g landed
        PROC4(c0);
        if (g + 2 < GROUPS) {
            ISSUE(c0, g + 2);           // outstanding: 8
            WAITCNT(4);                 // group g+1 landed
        } else {
            WAITCNT(0);                 // last group
        }
        PROC4(c1);
    }
#undef ISSUE
#undef PROC4

    sA = wave_reduce_sum(sA);
    sB = wave_reduce_sum(sB);
    t  = wave_reduce_sum(t);
    if (lane == 0) {
        atomicAdd(&SA[b], sA);
        atomicAdd(&SB[b], sB);
        atomicAdd(&Tacc[b], t);
    }

    __syncthreads();
    if (threadIdx.x < 2 * PHASE_BINS) {
        int hi  = threadIdx.x / PHASE_BINS;
        int bin = threadIdx.x % PHASE_BINS;
        unsigned v = h[hi][0][bin] + h[hi][1][bin] + h[hi][2][bin] + h[hi][3][bin];
        unsigned int* dst = hi ? histB : histA;
        atomicAdd(&dst[b * PHASE_BINS + bin], v);
    }
}

// pass2a: one wave per batch. Densities (fp32 torch edge widths), normalize,
// phase KL -> atomicAdd into phase_total; amplitude loss -> amp[b].
__global__ __launch_bounds__(64) void pass2a_kernel(
    const float* __restrict__ SA, const float* __restrict__ SB,
    const float* __restrict__ T,
    const unsigned int* __restrict__ histA, const unsigned int* __restrict__ histB,
    float* __restrict__ amp, float* __restrict__ phase_total)
{
    const int b = blockIdx.x;
    const int lane = threadIdx.x;
    const float PI_F = 3.14159265358979323846f;
    const float step = (2.0f * PI_F) / PHASE_BINS;

    float d_a[2], d_b[2];
    float sum_a = 0.f, sum_b = 0.f;
    #pragma unroll
    for (int r = 0; r < 2; ++r) {
        int bin = lane + r * 64;
        float da = 0.f, db = 0.f;
        if (bin < PHASE_BINS) {
            float e0 = -PI_F + bin * step;
            float e1 = (bin == PHASE_BINS - 1) ? PI_F : (-PI_F + (bin + 1) * step);
            float w = e1 - e0;                       // fp32 edge widths (torch density)
            float denom = (float)HW * w;
            da = (float)histA[b * PHASE_BINS + bin] / denom;
            db = (float)histB[b * PHASE_BINS + bin] / denom;
        }
        d_a[r] = da; d_b[r] = db;
        sum_a += da; sum_b += db;
    }
    #pragma unroll
    for (int off = 32; off > 0; off >>= 1) {
        sum_a += __shfl_xor(sum_a, off, 64);
        sum_b += __shfl_xor(sum_b, off, 64);
    }
    float kl = 0.f;
    #pragma unroll
    for (int r = 0; r < 2; ++r) {
        int bin = lane + r * 64;
        if (bin < PHASE_BINS) {
            float p = d_a[r] / (sum_a + EPSF);
            float q = d_b[r] / (sum_b + EPSF);
            kl += p * logf((p + EPSF) / (q + EPSF));
        }
    }
    #pragma unroll
    for (int off = 32; off > 0; off >>= 1) kl += __shfl_xor(kl, off, 64);

    if (lane == 0) {
        atomicAdd(phase_total, kl);
        float sa_raw = SA[b];
        float sa = sa_raw + EPSF;
        float sb = SB[b] + EPSF;
        // 0.34657359 = ln2/2 folded out of pass1's T accumulation
        amp[b] = (0.34657359028f * T[b]) / sa + (sa_raw / sa) * logf(sb / sa);
    }
}

__global__ __launch_bounds__(64) void pass2b_kernel(
    const float* __restrict__ amp, const float* __restrict__ phase_total,
    float* __restrict__ out)
{
    int b = threadIdx.x;
    out[b] = 0.5f * amp[b] + 0.5f * phase_total[0];
}

extern "C" void kernel_launch(void* const* d_in, const int* in_sizes, int n_in,
                              void* d_out, int out_size, void* d_ws, size_t ws_size,
                              hipStream_t stream) {
    const float* A = (const float*)d_in[0];
    const float* B = (const float*)d_in[1];
    float* out = (float*)d_out;

    float* SA = (float*)d_ws;
    float* SB = SA + BATCH;
    float* T  = SB + BATCH;
    unsigned int* histA = (unsigned int*)(T + BATCH);
    unsigned int* histB = histA + BATCH * PHASE_BINS;
    float* phase_total = (float*)(histB + BATCH * PHASE_BINS);
    float* amp = phase_total + 1;

    // zero SA/SB/T, both histograms, and phase_total
    size_t zero_bytes = (size_t)(3 * BATCH) * sizeof(float)
                      + (size_t)(2 * BATCH * PHASE_BINS) * sizeof(unsigned int)
                      + sizeof(float);
    hipMemsetAsync(d_ws, 0, zero_bytes, stream);

    pass1_kernel<<<dim3(BATCH * BPB), dim3(THREADS), 0, stream>>>(
        A, B, SA, SB, T, histA, histB);
    pass2a_kernel<<<dim3(BATCH), dim3(64), 0, stream>>>(
        SA, SB, T, histA, histB, amp, phase_total);
    pass2b_kernel<<<1, 64, 0, stream>>>(amp, phase_total, out);
}